// Round 3
// baseline (332.640 us; speedup 1.0000x reference)
//
#include <hip/hip_runtime.h>

#define B_   2
#define S_   2048
#define D_   1024
#define H_   16
#define DK_  64
#define DFF_ 4096
#define NTOK (B_ * S_)   // 4096

#define QSCALE 0.18033688011112042f   // 0.125 * log2(e)

typedef __bf16 bf16x8 __attribute__((ext_vector_type(8)));
typedef __bf16 bf16x4 __attribute__((ext_vector_type(4)));
typedef float  f32x4  __attribute__((ext_vector_type(4)));

#if __has_builtin(__builtin_amdgcn_exp2f)
#define EXP2(x) __builtin_amdgcn_exp2f(x)
#else
#define EXP2(x) exp2f(x)
#endif

// async global->LDS 16B copy. LDS dest is wave-uniform base + lane*16.
__device__ __forceinline__ void ld16(const __bf16* g, __bf16* l) {
  __builtin_amdgcn_global_load_lds(
      (const __attribute__((address_space(1))) void*)g,
      (__attribute__((address_space(3))) void*)l, 16, 0, 0);
}

// raw barrier: NO implicit vmcnt(0) drain.
#define RAW_BAR()     __asm__ __volatile__("s_barrier" ::: "memory")
#define SCHED_FENCE() __builtin_amdgcn_sched_barrier(0)

// XCD swizzle for 256^2-tile kernels. gy==16 in all uses.
// gx==16 (FFN1): chunk = 4 rows x 8 cols. gx==4 (QKV/FFN2/oproj per z):
// chunk = 2 rows x 4 cols (A 1MB + B 2MB per XCD -> fits 4MB L2).
__device__ __forceinline__ void xcd_swz256(int& bx, int& by) {
  const int gx = gridDim.x;
  const int flat = blockIdx.y * gx + blockIdx.x;
  const int x = flat & 7, n = flat >> 3;
  if (gx == 16) { by = ((x >> 1) << 2) + (n >> 3); bx = ((x & 1) << 3) + (n & 7); }
  else          { by = (x << 1) + (n >> 2);        bx = n & 3; }
}

// ---------------------------------------------------------------------------
// 256^2 8-phase GEMM core (T1+T2+T3+T4+T5). BM=BN=256, BK=64, 8 waves,
// per-wave C = 128x64 = acc[8][4]. LDS 128 KiB. Phase table: round-1 notes.
// ---------------------------------------------------------------------------
__device__ __forceinline__ void lda4(bf16x8 (&afr)[4], const __bf16* hb,
                                     int abase, int f0) {
#pragma unroll
  for (int i = 0; i < 4; ++i)
    afr[i] = *(const bf16x8*)(hb + abase + (f0 + i) * 512);
}

__device__ __forceinline__ void ldb4(bf16x8 (&bfr)[4], const __bf16* hb,
                                     int bbase) {
#pragma unroll
  for (int j = 0; j < 4; ++j)
    bfr[j] = *(const bf16x8*)(hb + bbase + j * 512);
}

__device__ __forceinline__ void mm16(f32x4 (&acc)[8][4], const bf16x8 (&afr)[4],
                                     const bf16x8 (&bfr)[4], int r0) {
#pragma unroll
  for (int i = 0; i < 4; ++i)
#pragma unroll
    for (int j = 0; j < 4; ++j)
      acc[r0 + i][j] =
          __builtin_amdgcn_mfma_f32_16x16x32_bf16(afr[i], bfr[j], acc[r0 + i][j], 0, 0, 0);
}

__device__ __forceinline__ void gemm_core_256(
    const __bf16* __restrict__ A, const __bf16* __restrict__ W,
    int ld, int kLen, int rowA0, int rowW0,
    f32x4 (&acc)[8][4], __bf16* Ls)
{
  const int t = threadIdx.x;
  const int lane = t & 63, wv = t >> 6;
  const int wm = wv >> 2, wn = wv & 3;
  const int l15 = lane & 15, q4 = lane >> 4;

  const int lane_rd = l15 * 32 + ((q4 * 8) ^ (((l15 >> 1) & 3) << 3));
  const int abase = wm * 4096 + lane_rd;   // + fr*512
  const int bbase = wn * 2048 + lane_rd;   // + fc*512

  const int sc0 = t ^ ((t >> 3) & 3);      // inverse-swizzled stage source
  const __bf16* gA0 = A + (size_t)(rowA0 + (sc0 >> 2)) * ld + (sc0 & 3) * 8;
  const __bf16* gA1 = gA0 + (size_t)128 * ld;
  const __bf16* gW0 = W + (size_t)(rowW0 + (sc0 >> 2)) * ld + (sc0 & 3) * 8;
  const __bf16* gW1 = gW0 + (size_t)128 * ld;
  const int d0 = wv * 512, d1 = 4096 + wv * 512;   // linear LDS dests

#pragma unroll
  for (int i = 0; i < 8; ++i)
#pragma unroll
    for (int j = 0; j < 4; ++j) acc[i][j] = (f32x4){0.f, 0.f, 0.f, 0.f};

#define HBASE(slot, mat, h) (Ls + ((((slot)*2) + (mat)) * 2 + (h)) * 8192)
#define STG_A(tt, h, slot) do { __bf16* _d = HBASE(slot, 0, h);              \
    const int _ko = (tt) * 64 + (h) * 32;                                    \
    ld16(gA0 + _ko, _d + d0); ld16(gA1 + _ko, _d + d1); } while (0)
#define STG_B(tt, h, slot) do { __bf16* _d = HBASE(slot, 1, h);              \
    const int _ko = (tt) * 64 + (h) * 32;                                    \
    ld16(gW0 + _ko, _d + d0); ld16(gW1 + _ko, _d + d1); } while (0)
#define MFMA_PH(r0) do { RAW_BAR(); SCHED_FENCE();                           \
    __builtin_amdgcn_s_setprio(1); mm16(acc, afr, bfr, r0);                  \
    __builtin_amdgcn_s_setprio(0); SCHED_FENCE(); RAW_BAR(); } while (0)

  const int NT = kLen >> 6;
  bf16x8 afr[4], bfr[4];

  STG_A(0, 0, 0); STG_A(0, 1, 0); STG_B(0, 0, 0); STG_B(0, 1, 0);
  STG_B(1, 0, 1); STG_A(1, 0, 1); STG_B(1, 1, 1);
  __asm__ __volatile__("s_waitcnt vmcnt(6)" ::: "memory");
  RAW_BAR(); SCHED_FENCE();

  for (int u = 0; u < NT; u += 2) {
    const bool g2 = (u + 2) < NT, g3 = (u + 3) < NT;
    // ph1
    lda4(afr, HBASE(0, 0, 0), abase, 0); ldb4(bfr, HBASE(0, 1, 0), bbase);
    STG_A(u + 1, 1, 1);
    MFMA_PH(0);
    // ph2
    lda4(afr, HBASE(0, 0, 0), abase, 4);
    if (g2) STG_B(u + 2, 0, 0);
    MFMA_PH(4);
    // ph3
    lda4(afr, HBASE(0, 0, 1), abase, 0); ldb4(bfr, HBASE(0, 1, 1), bbase);
    if (g2) STG_A(u + 2, 0, 0);
    MFMA_PH(0);
    // ph4
    lda4(afr, HBASE(0, 0, 1), abase, 4);
    if (g2) {
      STG_B(u + 2, 1, 0);
      __asm__ __volatile__("s_waitcnt vmcnt(6)" ::: "memory");
    } else {
      __asm__ __volatile__("s_waitcnt vmcnt(0)" ::: "memory");  // tail drain
    }
    MFMA_PH(4);
    // ph5
    lda4(afr, HBASE(1, 0, 0), abase, 0); ldb4(bfr, HBASE(1, 1, 0), bbase);
    if (g2) STG_A(u + 2, 1, 0);
    MFMA_PH(0);
    // ph6
    lda4(afr, HBASE(1, 0, 0), abase, 4);
    if (g3) STG_B(u + 3, 0, 1);
    MFMA_PH(4);
    // ph7
    lda4(afr, HBASE(1, 0, 1), abase, 0); ldb4(bfr, HBASE(1, 1, 1), bbase);
    if (g3) STG_A(u + 3, 0, 1);
    MFMA_PH(0);
    // ph8
    lda4(afr, HBASE(1, 0, 1), abase, 4);
    if (g3) STG_B(u + 3, 1, 1);
    __asm__ __volatile__("s_waitcnt vmcnt(6)" ::: "memory");
    MFMA_PH(4);
  }
#undef HBASE
#undef STG_A
#undef STG_B
#undef MFMA_PH
}

// ---------------------------------------------------------------------------
// QKV on the 256^2 core: grid (4,16,3). Q pre-scaled; V stored transposed.
// ---------------------------------------------------------------------------
__global__ __launch_bounds__(512, 2) void gemm_qkv_256(
    const __bf16* __restrict__ xn,
    const __bf16* __restrict__ wqb, const __bf16* __restrict__ wkb,
    const __bf16* __restrict__ wvb,
    __bf16* __restrict__ qo, __bf16* __restrict__ ko, __bf16* __restrict__ vto)
{
  __shared__ __align__(16) __bf16 Ls[65536];   // 128 KiB
  int bx, by; xcd_swz256(bx, by);
  const __bf16* W = blockIdx.z == 0 ? wqb : (blockIdx.z == 1 ? wkb : wvb);
  f32x4 acc[8][4];
  gemm_core_256(xn, W, D_, D_, by * 256, bx * 256, acc, Ls);

  const int t = threadIdx.x, lane = t & 63, wv = t >> 6;
  const int wm = wv >> 2, wn = wv & 3;
  const int l15 = lane & 15, q4 = lane >> 4;
  const int row0 = by * 256 + wm * 128;
  const int col0 = bx * 256 + wn * 64;

  if (blockIdx.z < 2) {
    __bf16* o = blockIdx.z == 0 ? qo : ko;
    const float sc = blockIdx.z == 0 ? QSCALE : 1.0f;
#pragma unroll
    for (int fr = 0; fr < 8; ++fr)
#pragma unroll
      for (int fc = 0; fc < 4; ++fc) {
        const int col = col0 + fc * 16 + l15;
#pragma unroll
        for (int r = 0; r < 4; ++r) {
          const int row = row0 + fr * 16 + q4 * 4 + r;
          o[(size_t)row * D_ + col] = (__bf16)(acc[fr][fc][r] * sc);
        }
      }
  } else {
#pragma unroll
    for (int fr = 0; fr < 8; ++fr)
#pragma unroll
      for (int fc = 0; fc < 4; ++fc) {
        const int tok0 = row0 + fr * 16 + q4 * 4;
        const int c    = col0 + fc * 16 + l15;
        const int b0 = tok0 >> 11, s0 = tok0 & (S_ - 1);
        const int hh = c >> 6, dd = c & (DK_ - 1);
        bf16x4 pk;
#pragma unroll
        for (int r = 0; r < 4; ++r) pk[r] = (__bf16)acc[fr][fc][r];
        *(bf16x4*)&vto[(size_t)((b0 * H_ + hh) * DK_ + dd) * S_ + s0] = pk;
      }
  }
}

// ---------------------------------------------------------------------------
// FFN1 on the 256^2 core: h = relu(A @ W1^T + b1). grid (16,16).
// ---------------------------------------------------------------------------
__global__ __launch_bounds__(512, 2) void gemm_ffn1_256(
    const __bf16* __restrict__ A, const __bf16* __restrict__ W,
    __bf16* __restrict__ outb, const float* __restrict__ bias)
{
  __shared__ __align__(16) __bf16 Ls[65536];
  int bx, by; xcd_swz256(bx, by);
  f32x4 acc[8][4];
  gemm_core_256(A, W, D_, D_, by * 256, bx * 256, acc, Ls);

  const int t = threadIdx.x, lane = t & 63, wv = t >> 6;
  const int wm = wv >> 2, wn = wv & 3;
  const int l15 = lane & 15, q4 = lane >> 4;
  const int row0 = by * 256 + wm * 128;
  const int col0 = bx * 256 + wn * 64;

#pragma unroll
  for (int fr = 0; fr < 8; ++fr)
#pragma unroll
    for (int fc = 0; fc < 4; ++fc) {
      const int col = col0 + fc * 16 + l15;
      const float bs = bias[col];
#pragma unroll
      for (int r = 0; r < 4; ++r) {
        const int row = row0 + fr * 16 + q4 * 4 + r;
        outb[(size_t)row * DFF_ + col] = (__bf16)fmaxf(acc[fr][fc][r] + bs, 0.0f);
      }
    }
}

// ---------------------------------------------------------------------------
// FFN2 on the 256^2 core, split-K=4: grid (4,16,4), bf16 partials contiguous.
// ---------------------------------------------------------------------------
__global__ __launch_bounds__(512, 2) void gemm_ffn2_sk4(
    const __bf16* __restrict__ A, const __bf16* __restrict__ W,
    __bf16* __restrict__ pp)
{
  __shared__ __align__(16) __bf16 Ls[65536];
  int bx, by; xcd_swz256(bx, by);
  const int z = blockIdx.z;
  f32x4 acc[8][4];
  gemm_core_256(A + (size_t)z * 1024, W + (size_t)z * 1024, DFF_, 1024,
                by * 256, bx * 256, acc, Ls);

  const int t = threadIdx.x, lane = t & 63, wv = t >> 6;
  const int wm = wv >> 2, wn = wv & 3;
  const int l15 = lane & 15, q4 = lane >> 4;
  const int row0 = by * 256 + wm * 128;
  const int col0 = bx * 256 + wn * 64;
  __bf16* out = pp + (size_t)z * NTOK * D_;

#pragma unroll
  for (int fr = 0; fr < 8; ++fr)
#pragma unroll
    for (int fc = 0; fc < 4; ++fc) {
      const int col = col0 + fc * 16 + l15;
#pragma unroll
      for (int r = 0; r < 4; ++r) {
        const int row = row0 + fr * 16 + q4 * 4 + r;
        out[(size_t)row * D_ + col] = (__bf16)acc[fr][fc][r];
      }
    }
}

// ---------------------------------------------------------------------------
// O-proj on the 256^2 core, split-K=2 (R3: was the last 128^2-core user at
// ~420 TF). grid (4,16,2) = 128 blocks, kLen=512 (NT=8), f32 partials.
// ---------------------------------------------------------------------------
__global__ __launch_bounds__(512, 2) void gemm_oproj_256(
    const __bf16* __restrict__ A, const __bf16* __restrict__ W,
    float* __restrict__ p0, float* __restrict__ p1)
{
  __shared__ __align__(16) __bf16 Ls[65536];
  int bx, by; xcd_swz256(bx, by);
  const int z = blockIdx.z;
  f32x4 acc[8][4];
  gemm_core_256(A + (size_t)z * 512, W + (size_t)z * 512, D_, 512,
                by * 256, bx * 256, acc, Ls);

  const int t = threadIdx.x, lane = t & 63, wv = t >> 6;
  const int wm = wv >> 2, wn = wv & 3;
  const int l15 = lane & 15, q4 = lane >> 4;
  const int row0 = by * 256 + wm * 128;
  const int col0 = bx * 256 + wn * 64;
  float* out = z == 0 ? p0 : p1;

#pragma unroll
  for (int fr = 0; fr < 8; ++fr)
#pragma unroll
    for (int fc = 0; fc < 4; ++fc) {
      const int col = col0 + fc * 16 + l15;
#pragma unroll
      for (int r = 0; r < 4; ++r) {
        const int row = row0 + fr * 16 + q4 * 4 + r;
        out[(size_t)row * D_ + col] = acc[fr][fc][r];
      }
    }
}

// ---------------------------------------------------------------------------
// O-proj reduce + LN2 fused: x1 = x + p0 + p1; xn2 = LN(x1). 1 block/row.
// ---------------------------------------------------------------------------
__global__ __launch_bounds__(256) void oproj_ln_reduce(
    const float* __restrict__ x, const float* __restrict__ p0,
    const float* __restrict__ p1, const float* __restrict__ alpha,
    const float* __restrict__ bias, float* __restrict__ x1,
    __bf16* __restrict__ xn2)
{
  const int row = blockIdx.x;
  const int t = threadIdx.x;
  const size_t base = (size_t)row * D_;
  float4 v  = ((const float4*)(x  + base))[t];
  const float4 a0 = ((const float4*)(p0 + base))[t];
  const float4 a1 = ((const float4*)(p1 + base))[t];
  v.x += a0.x + a1.x; v.y += a0.y + a1.y;
  v.z += a0.z + a1.z; v.w += a0.w + a1.w;
  ((float4*)(x1 + base))[t] = v;

  float s  = v.x + v.y + v.z + v.w;
  float ss = v.x * v.x + v.y * v.y + v.z * v.z + v.w * v.w;
#pragma unroll
  for (int m = 1; m < 64; m <<= 1) {
    s  += __shfl_xor(s, m);
    ss += __shfl_xor(ss, m);
  }
  __shared__ float red[8];
  if ((t & 63) == 0) { red[t >> 6] = s; red[4 + (t >> 6)] = ss; }
  __syncthreads();
  s  = red[0] + red[1] + red[2] + red[3];
  ss = red[4] + red[5] + red[6] + red[7];
  const float mean = s * (1.0f / D_);
  float var = (ss - (float)D_ * mean * mean) * (1.0f / (D_ - 1));
  var = fmaxf(var, 0.0f);
  const float inv = 1.0f / (sqrtf(var) + 1e-6f);
  const float4 al = ((const float4*)alpha)[t];
  const float4 bi = ((const float4*)bias)[t];
  bf16x4 o;
  o.x = (__bf16)(al.x * (v.x - mean) * inv + bi.x);
  o.y = (__bf16)(al.y * (v.y - mean) * inv + bi.y);
  o.z = (__bf16)(al.z * (v.z - mean) * inv + bi.z);
  o.w = (__bf16)(al.w * (v.w - mean) * inv + bi.w);
  ((bf16x4*)(xn2 + base))[t] = o;
}

// ---------------------------------------------------------------------------
// FFN2 reduce: out = x1 + b2 + sum of 4 bf16 partials (contiguous at pp).
// ---------------------------------------------------------------------------
__global__ __launch_bounds__(256) void ffn2_reduce(
    const float* __restrict__ x1, const __bf16* __restrict__ pp,
    const float* __restrict__ b2, float* __restrict__ out)
{
  const int idx4 = blockIdx.x * 256 + threadIdx.x;
  float4 v = ((const float4*)x1)[idx4];
  const float4 bs = ((const float4*)b2)[idx4 & 255];
  const size_t st = (size_t)NTOK * D_ / 4;
  const bf16x4 q0 = ((const bf16x4*)pp)[idx4];
  const bf16x4 q1 = ((const bf16x4*)pp)[idx4 + st];
  const bf16x4 q2 = ((const bf16x4*)pp)[idx4 + 2 * st];
  const bf16x4 q3 = ((const bf16x4*)pp)[idx4 + 3 * st];
  v.x += bs.x + (float)q0[0] + (float)q1[0] + (float)q2[0] + (float)q3[0];
  v.y += bs.y + (float)q0[1] + (float)q1[1] + (float)q2[1] + (float)q3[1];
  v.z += bs.z + (float)q0[2] + (float)q1[2] + (float)q2[2] + (float)q3[2];
  v.w += bs.w + (float)q0[3] + (float)q1[3] + (float)q2[3] + (float)q3[3];
  ((float4*)out)[idx4] = v;
}

// ---------------------------------------------------------------------------
// weight f32->bf16 casts (jobs 0-5) + fused LN1 (job 6) in one launch.
// ---------------------------------------------------------------------------
struct CastJobs {
  const float* src[6];
  __bf16* dst[6];
  int n4[6];
};

__global__ __launch_bounds__(256) void cast_ln_kernel(
    CastJobs cj, const float* __restrict__ x, const float* __restrict__ alpha,
    const float* __restrict__ bias, __bf16* __restrict__ xn1)
{
  const int j = blockIdx.y;
  if (j < 6) {
    const int i = blockIdx.x * 256 + threadIdx.x;
    if (i < cj.n4[j]) {
      float4 v = ((const float4*)cj.src[j])[i];
      bf16x4 o;
      o.x = (__bf16)v.x; o.y = (__bf16)v.y; o.z = (__bf16)v.z; o.w = (__bf16)v.w;
      ((bf16x4*)cj.dst[j])[i] = o;
    }
    return;
  }
  const int row = blockIdx.x;
  const int t = threadIdx.x;
  const float4 v = ((const float4*)(x + (size_t)row * D_))[t];
  float s  = v.x + v.y + v.z + v.w;
  float ss = v.x * v.x + v.y * v.y + v.z * v.z + v.w * v.w;
#pragma unroll
  for (int m = 1; m < 64; m <<= 1) {
    s  += __shfl_xor(s, m);
    ss += __shfl_xor(ss, m);
  }
  __shared__ float red[8];
  if ((t & 63) == 0) { red[t >> 6] = s; red[4 + (t >> 6)] = ss; }
  __syncthreads();
  s  = red[0] + red[1] + red[2] + red[3];
  ss = red[4] + red[5] + red[6] + red[7];
  const float mean = s * (1.0f / D_);
  float var = (ss - (float)D_ * mean * mean) * (1.0f / (D_ - 1));
  var = fmaxf(var, 0.0f);
  const float inv = 1.0f / (sqrtf(var) + 1e-6f);
  const float4 al = ((const float4*)alpha)[t];
  const float4 bi = ((const float4*)bias)[t];
  bf16x4 o;
  o.x = (__bf16)(al.x * (v.x - mean) * inv + bi.x);
  o.y = (__bf16)(al.y * (v.y - mean) * inv + bi.y);
  o.z = (__bf16)(al.z * (v.z - mean) * inv + bi.z);
  o.w = (__bf16)(al.w * (v.w - mean) * inv + bi.w);
  ((bf16x4*)(xn1 + (size_t)row * D_))[t] = o;
}

// ---------------------------------------------------------------------------
// flash attention, BQ=128. R3: l-sum moved off the VALU onto the MFMA pipe
// via P @ ones (4 extra MFMA/iter replace 32 dependent v_add chains AND the
// end-of-kernel shuffle transpose: ones-MFMA C-layout row=q4*4+r lands 1/l
// already in O-row ownership). blockDirty register hoist: clean-mask path
// never reads Dd LDS per iter. K/V dbuf + single barrier per iter (R2).
// ---------------------------------------------------------------------------
__global__ __launch_bounds__(256) void attn_kernel(
    const __bf16* __restrict__ qg, const __bf16* __restrict__ kg,
    const __bf16* __restrict__ vtg, const int* __restrict__ mask,
    __bf16* __restrict__ av)
{
  __shared__ __align__(16) __bf16 Ks[2][64 * 64];  // 16 KB
  __shared__ __align__(16) __bf16 Vt[2][64 * 64];  // 16 KB
  __shared__ __align__(16) __bf16 Ps[128 * 72];    // 18 KB (Q overlay at start)
  __shared__ int Dd[32];                           // per-kv-chunk dirty flags

  const int t = threadIdx.x, lane = t & 63, wv = t >> 6;
  const int l15 = lane & 15, q4 = lane >> 4;
  const int bh = blockIdx.x;
  const int b = bh >> 4, h = bh & (H_ - 1);
  const int q0 = blockIdx.y * 128;

  const int srow = lane & 7, sc8 = lane >> 3;
  const __bf16* qg0 = qg + (size_t)(b * S_ + q0 + 32 * wv + srow) * D_ + h * DK_ + sc8 * 8;
  __bf16* lQ = Ps + wv * 2304;
#pragma unroll
  for (int p = 0; p < 4; ++p)
    ld16(qg0 + (size_t)(8 * p) * D_, lQ + 512 * p);

  const __bf16* kg0 = kg + (size_t)(b * S_ + 16 * wv + srow) * D_ + h * DK_ + sc8 * 8;
  const __bf16* vt0 = vtg + (size_t)(bh * DK_ + 16 * wv + srow) * S_ + sc8 * 8;

  if (t < 32) Dd[t] = 0;

  // stage kv-tile 0 into buf 0
  ld16(kg0,                  Ks[0] + wv * 1024);
  ld16(kg0 + (size_t)8 * D_, Ks[0] + wv * 1024 + 512);
  ld16(vt0,                  Vt[0] + wv * 1024);
  ld16(vt0 + (size_t)8 * S_, Vt[0] + wv * 1024 + 512);

  __syncthreads();   // Dd init visible; drains Q/KV0 staging

  // one-time mask scan: thread t covers kv = 8t..8t+8 (chunk t>>3)
  {
    const int4* m4 = (const int4*)(mask + (size_t)b * S_) + t * 2;
    const int4 a = m4[0], c = m4[1];
    const bool anyz = (a.x == 0) | (a.y == 0) | (a.z == 0) | (a.w == 0) |
                      (c.x == 0) | (c.y == 0) | (c.z == 0) | (c.w == 0);
    if (anyz) Dd[t >> 3] = 1;
  }
  __syncthreads();
  // uniform register flag: any chunk dirty? (wave's 64 lanes cover all 32)
  const bool blockDirty = (__ballot(Dd[lane & 31] != 0) != 0ull);

  const int fb = ((l15 >> 3) << 9) + (q4 << 6) + ((l15 & 7) << 3);
  const int mrow = b * S_;

  // Q B-frags from wave-private overlay
  bf16x8 bq[2][2];
#pragma unroll
  for (int j = 0; j < 2; ++j)
#pragma unroll
    for (int s = 0; s < 2; ++s)
      bq[j][s] = *(const bf16x8*)(lQ + j * 1024 + s * 256 + fb);

  // all-ones B-frag for the l-sum MFMA
  bf16x8 bones;
#pragma unroll
  for (int e = 0; e < 8; ++e) bones[e] = (__bf16)1.0f;

  f32x4 lacc[2];
  f32x4 oacc[2][4];
#pragma unroll
  for (int m = 0; m < 2; ++m) {
    lacc[m] = (f32x4){0.f, 0.f, 0.f, 0.f};
#pragma unroll
    for (int jd = 0; jd < 4; ++jd) oacc[m][jd] = (f32x4){0.f, 0.f, 0.f, 0.f};
  }

  for (int kv0 = 0; kv0 < S_; kv0 += 64) {
    const int buf = (kv0 >> 6) & 1;
    // prefetch next kv-tile into buf^1 (flies under the whole compute phase)
    if (kv0 + 64 < S_) {
      const size_t nk = (size_t)(kv0 + 64);
      ld16(kg0 + nk * D_,              Ks[buf ^ 1] + wv * 1024);
      ld16(kg0 + (nk + 8) * D_,        Ks[buf ^ 1] + wv * 1024 + 512);
      ld16(vt0 + nk,                   Vt[buf ^ 1] + wv * 1024);
      ld16(vt0 + (size_t)8 * S_ + nk,  Vt[buf ^ 1] + wv * 1024 + 512);
    }

    // S^T = K Q^T : rows kv (4 i-tiles), cols q (wave's 2 j-slices of 16)
    f32x4 sacc[4][2];
#pragma unroll
    for (int i = 0; i < 4; ++i)
#pragma unroll
      for (int j = 0; j < 2; ++j) sacc[i][j] = (f32x4){0.f, 0.f, 0.f, 0.f};
    __builtin_amdgcn_s_setprio(1);
#pragma unroll
    for (int i = 0; i < 4; ++i)
#pragma unroll
      for (int s = 0; s < 2; ++s) {
        bf16x8 ak = *(const bf16x8*)(Ks[buf] + i * 1024 + fb + s * 256);
#pragma unroll
        for (int j = 0; j < 2; ++j)
          sacc[i][j] = __builtin_amdgcn_mfma_f32_16x16x32_bf16(ak, bq[j][s], sacc[i][j], 0, 0, 0);
      }
    __builtin_amdgcn_s_setprio(0);

    if (blockDirty && Dd[kv0 >> 6]) {   // cold path (all-ones mask: never)
#pragma unroll
      for (int i = 0; i < 4; ++i)
#pragma unroll
        for (int r = 0; r < 4; ++r)
          if (mask[mrow + kv0 + 16 * i + 4 * q4 + r] == 0) {
            sacc[i][0][r] = -1e30f;
            sacc[i][1][r] = -1e30f;
          }
    }

    // fixed-max softmax; P -> Ps rows q (wave-local); no VALU l-sum
#pragma unroll
    for (int j = 0; j < 2; ++j)
#pragma unroll
      for (int i = 0; i < 4; ++i) {
        bf16x4 pb;
#pragma unroll
        for (int r = 0; r < 4; ++r) pb[r] = (__bf16)EXP2(sacc[i][j][r]);
        *(bf16x4*)(Ps + (wv * 32 + j * 16 + l15) * 72 + 16 * i + q4 * 4) = pb;
      }

    // O += P V ; l += P @ ones (MFMA-pipe row-sum)
    bf16x8 ap[2][2];
#pragma unroll
    for (int m = 0; m < 2; ++m)
#pragma unroll
      for (int s = 0; s < 2; ++s)
        ap[m][s] = *(const bf16x8*)(Ps + (wv * 32 + 16 * m + l15) * 72 + s * 32 + q4 * 8);
    __builtin_amdgcn_s_setprio(1);
#pragma unroll
    for (int jd = 0; jd < 4; ++jd)
#pragma unroll
      for (int s = 0; s < 2; ++s) {
        bf16x8 bv = *(const bf16x8*)(Vt[buf] + jd * 1024 + fb + s * 256);
#pragma unroll
        for (int m = 0; m < 2; ++m)
          oacc[m][jd] = __builtin_amdgcn_mfma_f32_16x16x32_bf16(ap[m][s], bv, oacc[m][jd], 0, 0, 0);
      }
#pragma unroll
    for (int m = 0; m < 2; ++m)
#pragma unroll
      for (int s = 0; s < 2; ++s)
        lacc[m] = __builtin_amdgcn_mfma_f32_16x16x32_bf16(ap[m][s], bones, lacc[m], 0, 0, 0);
    __builtin_amdgcn_s_setprio(0);

    __syncthreads();   // drains prefetch (RAW) + proves buf read done (WAR)
  }

  // lacc[m][r] = l for q-row (wv*32 + 16m + q4*4 + r) — already O-row-owned.
#pragma unroll
  for (int m = 0; m < 2; ++m) {
    f32x4 lt;
#pragma unroll
    for (int r = 0; r < 4; ++r) lt[r] = 1.0f / lacc[m][r];
#pragma unroll
    for (int jd = 0; jd < 4; ++jd)
#pragma unroll
      for (int r = 0; r < 4; ++r) {
        int tok = b * S_ + q0 + wv * 32 + 16 * m + q4 * 4 + r;
        int c   = h * DK_ + jd * 16 + l15;
        av[(size_t)tok * D_ + c] = (__bf16)(oacc[m][jd][r] * lt[r]);
      }
  }
}

// ---------------------------------------------------------------------------
extern "C" void kernel_launch(void* const* d_in, const int* in_sizes, int n_in,
                              void* d_out, int out_size, void* d_ws, size_t ws_size,
                              hipStream_t stream) {
  const float* x      = (const float*)d_in[0];
  const int*   mask   = (const int*)d_in[1];
  const float* wq     = (const float*)d_in[2];
  const float* wk     = (const float*)d_in[3];
  const float* wv     = (const float*)d_in[4];
  const float* wo     = (const float*)d_in[5];
  const float* w1     = (const float*)d_in[6];
  const float* b1     = (const float*)d_in[7];
  const float* w2     = (const float*)d_in[8];
  const float* b2     = (const float*)d_in[9];
  const float* alpha1 = (const float*)d_in[10];
  const float* bias1  = (const float*)d_in[11];
  const float* alpha2 = (const float*)d_in[12];
  const float* bias2  = (const float*)d_in[13];

  char* ws = (char*)d_ws;
  __bf16* wqb = (__bf16*)(ws + ((size_t)0 << 20));
  __bf16* wkb = (__bf16*)(ws + ((size_t)2 << 20));
  __bf16* wvb = (__bf16*)(ws + ((size_t)4 << 20));
  __bf16* wob = (__bf16*)(ws + ((size_t)6 << 20));
  __bf16* w1b = (__bf16*)(ws + ((size_t)8 << 20));
  __bf16* w2b = (__bf16*)(ws + ((size_t)16 << 20));
  __bf16* xn1 = (__bf16*)(ws + ((size_t)24 << 20));
  __bf16* qb  = (__bf16*)(ws + ((size_t)32 << 20));
  __bf16* kb  = (__bf16*)(ws + ((size_t)40 << 20));
  __bf16* vtb = (__bf16*)(ws + ((size_t)48 << 20));
  __bf16* avb = (__bf16*)(ws + ((size_t)56 << 20));
  float*  x1  = (float*) (ws + ((size_t)64 << 20));
  __bf16* xn2 = (__bf16*)(ws + ((size_t)56 << 20));   // over avb (consumed)
  __bf16* hb  = (__bf16*)(ws + ((size_t)24 << 20));   // over xn1/op0 head
  float*  op0 = (float*) (ws + ((size_t)24 << 20));
  float*  op1 = (float*) (ws + ((size_t)40 << 20));
  __bf16* fpp = (__bf16*)(ws + ((size_t)32 << 20));   // ffn2 partials 4x8MB

  CastJobs cj;
  cj.src[0] = wq; cj.dst[0] = wqb; cj.n4[0] = D_ * D_ / 4;
  cj.src[1] = wk; cj.dst[1] = wkb; cj.n4[1] = D_ * D_ / 4;
  cj.src[2] = wv; cj.dst[2] = wvb; cj.n4[2] = D_ * D_ / 4;
  cj.src[3] = wo; cj.dst[3] = wob; cj.n4[3] = D_ * D_ / 4;
  cj.src[4] = w1; cj.dst[4] = w1b; cj.n4[4] = DFF_ * D_ / 4;
  cj.src[5] = w2; cj.dst[5] = w2b; cj.n4[5] = DFF_ * D_ / 4;

  cast_ln_kernel<<<dim3(DFF_ * D_ / 4 / 256, 7), 256, 0, stream>>>(
      cj, x, alpha1, bias1, xn1);

  gemm_qkv_256<<<dim3(D_ / 256, NTOK / 256, 3), 512, 0, stream>>>(
      xn1, wqb, wkb, wvb, qb, kb, vtb);

  attn_kernel<<<dim3(B_ * H_, S_ / 128), 256, 0, stream>>>(qb, kb, vtb, mask, avb);

  gemm_oproj_256<<<dim3(D_ / 256, NTOK / 256, 2), 512, 0, stream>>>(
      avb, wob, op0, op1);

  oproj_ln_reduce<<<dim3(NTOK), 256, 0, stream>>>(
      x, op0, op1, alpha2, bias2, x1, xn2);

  gemm_ffn1_256<<<dim3(DFF_ / 256, NTOK / 256), 512, 0, stream>>>(
      xn2, w1b, hb, b1);

  gemm_ffn2_sk4<<<dim3(D_ / 256, NTOK / 256, 4), 512, 0, stream>>>(
      hb, w2b, fpp);

  ffn2_reduce<<<dim3(NTOK * D_ / 4 / 256), 256, 0, stream>>>(
      x1, fpp, b2, (float*)d_out);
}

// Round 4
// 322.610 us; speedup vs baseline: 1.0311x; 1.0311x over previous
//
#include <hip/hip_runtime.h>

#define B_   2
#define S_   2048
#define D_   1024
#define H_   16
#define DK_  64
#define DFF_ 4096
#define NTOK (B_ * S_)   // 4096

#define QSCALE 0.18033688011112042f   // 0.125 * log2(e)

typedef __bf16 bf16x8 __attribute__((ext_vector_type(8)));
typedef __bf16 bf16x4 __attribute__((ext_vector_type(4)));
typedef __bf16 bf16x2 __attribute__((ext_vector_type(2)));
typedef float  f32x4  __attribute__((ext_vector_type(4)));
typedef int    i32x4  __attribute__((ext_vector_type(4)));

#if __has_builtin(__builtin_amdgcn_exp2f)
#define EXP2(x) __builtin_amdgcn_exp2f(x)
#else
#define EXP2(x) exp2f(x)
#endif

// async global->LDS 16B copy. LDS dest is wave-uniform base + lane*16.
__device__ __forceinline__ void ld16(const __bf16* g, __bf16* l) {
  __builtin_amdgcn_global_load_lds(
      (const __attribute__((address_space(1))) void*)g,
      (__attribute__((address_space(3))) void*)l, 16, 0, 0);
}

// raw barrier: NO implicit vmcnt(0) drain.
#define RAW_BAR()     __asm__ __volatile__("s_barrier" ::: "memory")
#define SCHED_FENCE() __builtin_amdgcn_sched_barrier(0)

// pack two f32 -> one u32 of 2 bf16 (compiler emits v_cvt_pk_bf16_f32)
__device__ __forceinline__ int packbf(float lo, float hi) {
  bf16x2 r; r[0] = (__bf16)lo; r[1] = (__bf16)hi;
  return __builtin_bit_cast(int, r);
}

// (a,b) -> (g0={a_lo32,b_lo32}, g1={a_hi32,b_hi32})
__device__ __forceinline__ void swap32(int a, int b, int& g0, int& g1, bool hi32) {
#if __has_builtin(__builtin_amdgcn_permlane32_swap)
  auto r = __builtin_amdgcn_permlane32_swap(a, b, false, false);
  g0 = r[0]; g1 = r[1];
  (void)hi32;
#else
  const int sa = __builtin_amdgcn_ds_swizzle(a, 0x801F);  // lane^32
  const int sb = __builtin_amdgcn_ds_swizzle(b, 0x801F);
  g0 = hi32 ? sb : a;
  g1 = hi32 ? b : sa;
#endif
}

// (a,b) -> (h0={a.r0,b.r0,a.r2,b.r2}, h1={a.r1,b.r1,a.r3,b.r3})  (16-lane rows)
__device__ __forceinline__ void swap16(int a, int b, int& h0, int& h1, bool hi16) {
#if __has_builtin(__builtin_amdgcn_permlane16_swap)
  auto r = __builtin_amdgcn_permlane16_swap(a, b, false, false);
  h0 = r[0]; h1 = r[1];
  (void)hi16;
#else
  const int sa = __builtin_amdgcn_ds_swizzle(a, 0x401F);  // lane^16
  const int sb = __builtin_amdgcn_ds_swizzle(b, 0x401F);
  h0 = hi16 ? sb : a;
  h1 = hi16 ? b : sa;
#endif
}

// XCD swizzle for 256^2-tile kernels. gy==16 in all uses.
__device__ __forceinline__ void xcd_swz256(int& bx, int& by) {
  const int gx = gridDim.x;
  const int flat = blockIdx.y * gx + blockIdx.x;
  const int x = flat & 7, n = flat >> 3;
  if (gx == 16) { by = ((x >> 1) << 2) + (n >> 3); bx = ((x & 1) << 3) + (n & 7); }
  else          { by = (x << 1) + (n >> 2);        bx = n & 3; }
}

// ---------------------------------------------------------------------------
// 256^2 8-phase GEMM core (T1+T2+T3+T4+T5). BM=BN=256, BK=64, 8 waves,
// per-wave C = 128x64 = acc[8][4]. LDS 128 KiB. Phase table: round-1 notes.
// ---------------------------------------------------------------------------
__device__ __forceinline__ void lda4(bf16x8 (&afr)[4], const __bf16* hb,
                                     int abase, int f0) {
#pragma unroll
  for (int i = 0; i < 4; ++i)
    afr[i] = *(const bf16x8*)(hb + abase + (f0 + i) * 512);
}

__device__ __forceinline__ void ldb4(bf16x8 (&bfr)[4], const __bf16* hb,
                                     int bbase) {
#pragma unroll
  for (int j = 0; j < 4; ++j)
    bfr[j] = *(const bf16x8*)(hb + bbase + j * 512);
}

__device__ __forceinline__ void mm16(f32x4 (&acc)[8][4], const bf16x8 (&afr)[4],
                                     const bf16x8 (&bfr)[4], int r0) {
#pragma unroll
  for (int i = 0; i < 4; ++i)
#pragma unroll
    for (int j = 0; j < 4; ++j)
      acc[r0 + i][j] =
          __builtin_amdgcn_mfma_f32_16x16x32_bf16(afr[i], bfr[j], acc[r0 + i][j], 0, 0, 0);
}

__device__ __forceinline__ void gemm_core_256(
    const __bf16* __restrict__ A, const __bf16* __restrict__ W,
    int ld, int kLen, int rowA0, int rowW0,
    f32x4 (&acc)[8][4], __bf16* Ls)
{
  const int t = threadIdx.x;
  const int lane = t & 63, wv = t >> 6;
  const int wm = wv >> 2, wn = wv & 3;
  const int l15 = lane & 15, q4 = lane >> 4;

  const int lane_rd = l15 * 32 + ((q4 * 8) ^ (((l15 >> 1) & 3) << 3));
  const int abase = wm * 4096 + lane_rd;   // + fr*512
  const int bbase = wn * 2048 + lane_rd;   // + fc*512

  const int sc0 = t ^ ((t >> 3) & 3);      // inverse-swizzled stage source
  const __bf16* gA0 = A + (size_t)(rowA0 + (sc0 >> 2)) * ld + (sc0 & 3) * 8;
  const __bf16* gA1 = gA0 + (size_t)128 * ld;
  const __bf16* gW0 = W + (size_t)(rowW0 + (sc0 >> 2)) * ld + (sc0 & 3) * 8;
  const __bf16* gW1 = gW0 + (size_t)128 * ld;
  const int d0 = wv * 512, d1 = 4096 + wv * 512;   // linear LDS dests

#pragma unroll
  for (int i = 0; i < 8; ++i)
#pragma unroll
    for (int j = 0; j < 4; ++j) acc[i][j] = (f32x4){0.f, 0.f, 0.f, 0.f};

#define HBASE(slot, mat, h) (Ls + ((((slot)*2) + (mat)) * 2 + (h)) * 8192)
#define STG_A(tt, h, slot) do { __bf16* _d = HBASE(slot, 0, h);              \
    const int _ko = (tt) * 64 + (h) * 32;                                    \
    ld16(gA0 + _ko, _d + d0); ld16(gA1 + _ko, _d + d1); } while (0)
#define STG_B(tt, h, slot) do { __bf16* _d = HBASE(slot, 1, h);              \
    const int _ko = (tt) * 64 + (h) * 32;                                    \
    ld16(gW0 + _ko, _d + d0); ld16(gW1 + _ko, _d + d1); } while (0)
#define MFMA_PH(r0) do { RAW_BAR(); SCHED_FENCE();                           \
    __builtin_amdgcn_s_setprio(1); mm16(acc, afr, bfr, r0);                  \
    __builtin_amdgcn_s_setprio(0); SCHED_FENCE(); RAW_BAR(); } while (0)

  const int NT = kLen >> 6;
  bf16x8 afr[4], bfr[4];

  STG_A(0, 0, 0); STG_A(0, 1, 0); STG_B(0, 0, 0); STG_B(0, 1, 0);
  STG_B(1, 0, 1); STG_A(1, 0, 1); STG_B(1, 1, 1);
  __asm__ __volatile__("s_waitcnt vmcnt(6)" ::: "memory");
  RAW_BAR(); SCHED_FENCE();

  for (int u = 0; u < NT; u += 2) {
    const bool g2 = (u + 2) < NT, g3 = (u + 3) < NT;
    // ph1
    lda4(afr, HBASE(0, 0, 0), abase, 0); ldb4(bfr, HBASE(0, 1, 0), bbase);
    STG_A(u + 1, 1, 1);
    MFMA_PH(0);
    // ph2
    lda4(afr, HBASE(0, 0, 0), abase, 4);
    if (g2) STG_B(u + 2, 0, 0);
    MFMA_PH(4);
    // ph3
    lda4(afr, HBASE(0, 0, 1), abase, 0); ldb4(bfr, HBASE(0, 1, 1), bbase);
    if (g2) STG_A(u + 2, 0, 0);
    MFMA_PH(0);
    // ph4
    lda4(afr, HBASE(0, 0, 1), abase, 4);
    if (g2) {
      STG_B(u + 2, 1, 0);
      __asm__ __volatile__("s_waitcnt vmcnt(6)" ::: "memory");
    } else {
      __asm__ __volatile__("s_waitcnt vmcnt(0)" ::: "memory");  // tail drain
    }
    MFMA_PH(4);
    // ph5
    lda4(afr, HBASE(1, 0, 0), abase, 0); ldb4(bfr, HBASE(1, 1, 0), bbase);
    if (g2) STG_A(u + 2, 1, 0);
    MFMA_PH(0);
    // ph6
    lda4(afr, HBASE(1, 0, 0), abase, 4);
    if (g3) STG_B(u + 3, 0, 1);
    MFMA_PH(4);
    // ph7
    lda4(afr, HBASE(1, 0, 1), abase, 0); ldb4(bfr, HBASE(1, 1, 1), bbase);
    if (g3) STG_A(u + 3, 0, 1);
    MFMA_PH(0);
    // ph8
    lda4(afr, HBASE(1, 0, 1), abase, 4);
    if (g3) STG_B(u + 3, 1, 1);
    __asm__ __volatile__("s_waitcnt vmcnt(6)" ::: "memory");
    MFMA_PH(4);
  }
#undef HBASE
#undef STG_A
#undef STG_B
#undef MFMA_PH
}

// ---------------------------------------------------------------------------
// QKV on the 256^2 core: grid (4,16,3). Q pre-scaled; V stored transposed.
// ---------------------------------------------------------------------------
__global__ __launch_bounds__(512, 2) void gemm_qkv_256(
    const __bf16* __restrict__ xn,
    const __bf16* __restrict__ wqb, const __bf16* __restrict__ wkb,
    const __bf16* __restrict__ wvb,
    __bf16* __restrict__ qo, __bf16* __restrict__ ko, __bf16* __restrict__ vto)
{
  __shared__ __align__(16) __bf16 Ls[65536];   // 128 KiB
  int bx, by; xcd_swz256(bx, by);
  const __bf16* W = blockIdx.z == 0 ? wqb : (blockIdx.z == 1 ? wkb : wvb);
  f32x4 acc[8][4];
  gemm_core_256(xn, W, D_, D_, by * 256, bx * 256, acc, Ls);

  const int t = threadIdx.x, lane = t & 63, wv = t >> 6;
  const int wm = wv >> 2, wn = wv & 3;
  const int l15 = lane & 15, q4 = lane >> 4;
  const int row0 = by * 256 + wm * 128;
  const int col0 = bx * 256 + wn * 64;

  if (blockIdx.z < 2) {
    __bf16* o = blockIdx.z == 0 ? qo : ko;
    const float sc = blockIdx.z == 0 ? QSCALE : 1.0f;
#pragma unroll
    for (int fr = 0; fr < 8; ++fr)
#pragma unroll
      for (int fc = 0; fc < 4; ++fc) {
        const int col = col0 + fc * 16 + l15;
#pragma unroll
        for (int r = 0; r < 4; ++r) {
          const int row = row0 + fr * 16 + q4 * 4 + r;
          o[(size_t)row * D_ + col] = (__bf16)(acc[fr][fc][r] * sc);
        }
      }
  } else {
#pragma unroll
    for (int fr = 0; fr < 8; ++fr)
#pragma unroll
      for (int fc = 0; fc < 4; ++fc) {
        const int tok0 = row0 + fr * 16 + q4 * 4;
        const int c    = col0 + fc * 16 + l15;
        const int b0 = tok0 >> 11, s0 = tok0 & (S_ - 1);
        const int hh = c >> 6, dd = c & (DK_ - 1);
        bf16x4 pk;
#pragma unroll
        for (int r = 0; r < 4; ++r) pk[r] = (__bf16)acc[fr][fc][r];
        *(bf16x4*)&vto[(size_t)((b0 * H_ + hh) * DK_ + dd) * S_ + s0] = pk;
      }
  }
}

// ---------------------------------------------------------------------------
// FFN1 on the 256^2 core: h = relu(A @ W1^T + b1). grid (16,16).
// ---------------------------------------------------------------------------
__global__ __launch_bounds__(512, 2) void gemm_ffn1_256(
    const __bf16* __restrict__ A, const __bf16* __restrict__ W,
    __bf16* __restrict__ outb, const float* __restrict__ bias)
{
  __shared__ __align__(16) __bf16 Ls[65536];
  int bx, by; xcd_swz256(bx, by);
  f32x4 acc[8][4];
  gemm_core_256(A, W, D_, D_, by * 256, bx * 256, acc, Ls);

  const int t = threadIdx.x, lane = t & 63, wv = t >> 6;
  const int wm = wv >> 2, wn = wv & 3;
  const int l15 = lane & 15, q4 = lane >> 4;
  const int row0 = by * 256 + wm * 128;
  const int col0 = bx * 256 + wn * 64;

#pragma unroll
  for (int fr = 0; fr < 8; ++fr)
#pragma unroll
    for (int fc = 0; fc < 4; ++fc) {
      const int col = col0 + fc * 16 + l15;
      const float bs = bias[col];
#pragma unroll
      for (int r = 0; r < 4; ++r) {
        const int row = row0 + fr * 16 + q4 * 4 + r;
        outb[(size_t)row * DFF_ + col] = (__bf16)fmaxf(acc[fr][fc][r] + bs, 0.0f);
      }
    }
}

// ---------------------------------------------------------------------------
// FFN2 on the 256^2 core, split-K=4: grid (4,16,4). Partials go to four
// separate dead 8MB regions (R4: fixes the fpp/hb overlap race).
// ---------------------------------------------------------------------------
__global__ __launch_bounds__(512, 2) void gemm_ffn2_sk4(
    const __bf16* __restrict__ A, const __bf16* __restrict__ W,
    __bf16* __restrict__ p0, __bf16* __restrict__ p1,
    __bf16* __restrict__ p2, __bf16* __restrict__ p3)
{
  __shared__ __align__(16) __bf16 Ls[65536];
  int bx, by; xcd_swz256(bx, by);
  const int z = blockIdx.z;
  f32x4 acc[8][4];
  gemm_core_256(A + (size_t)z * 1024, W + (size_t)z * 1024, DFF_, 1024,
                by * 256, bx * 256, acc, Ls);

  const int t = threadIdx.x, lane = t & 63, wv = t >> 6;
  const int wm = wv >> 2, wn = wv & 3;
  const int l15 = lane & 15, q4 = lane >> 4;
  const int row0 = by * 256 + wm * 128;
  const int col0 = bx * 256 + wn * 64;
  __bf16* out = z == 0 ? p0 : (z == 1 ? p1 : (z == 2 ? p2 : p3));

#pragma unroll
  for (int fr = 0; fr < 8; ++fr)
#pragma unroll
    for (int fc = 0; fc < 4; ++fc) {
      const int col = col0 + fc * 16 + l15;
#pragma unroll
      for (int r = 0; r < 4; ++r) {
        const int row = row0 + fr * 16 + q4 * 4 + r;
        out[(size_t)row * D_ + col] = (__bf16)acc[fr][fc][r];
      }
    }
}

// ---------------------------------------------------------------------------
// O-proj on the 256^2 core, split-K=4 (R4: 256 blocks, all CUs; R3's sk2 had
// half the GPU idle). bf16 partials contiguous 4x8MB.
// ---------------------------------------------------------------------------
__global__ __launch_bounds__(512, 2) void gemm_oproj_sk4(
    const __bf16* __restrict__ A, const __bf16* __restrict__ W,
    __bf16* __restrict__ pp)
{
  __shared__ __align__(16) __bf16 Ls[65536];
  int bx, by; xcd_swz256(bx, by);
  const int z = blockIdx.z;
  f32x4 acc[8][4];
  gemm_core_256(A + (size_t)z * 256, W + (size_t)z * 256, D_, 256,
                by * 256, bx * 256, acc, Ls);

  const int t = threadIdx.x, lane = t & 63, wv = t >> 6;
  const int wm = wv >> 2, wn = wv & 3;
  const int l15 = lane & 15, q4 = lane >> 4;
  const int row0 = by * 256 + wm * 128;
  const int col0 = bx * 256 + wn * 64;
  __bf16* out = pp + (size_t)z * NTOK * D_;

#pragma unroll
  for (int fr = 0; fr < 8; ++fr)
#pragma unroll
    for (int fc = 0; fc < 4; ++fc) {
      const int col = col0 + fc * 16 + l15;
#pragma unroll
      for (int r = 0; r < 4; ++r) {
        const int row = row0 + fr * 16 + q4 * 4 + r;
        out[(size_t)row * D_ + col] = (__bf16)acc[fr][fc][r];
      }
    }
}

// ---------------------------------------------------------------------------
// O-proj reduce + LN2 + d_out prefill: x1 = x + sum(4 bf16 partials);
// d_out = x1 + b2 (ffn2 residual base); xn2 = LN(x1). 1 block/row.
// ---------------------------------------------------------------------------
__global__ __launch_bounds__(256) void oproj_ln_reduce(
    const float* __restrict__ x, const __bf16* __restrict__ opp,
    const float* __restrict__ alpha, const float* __restrict__ bias,
    const float* __restrict__ b2, float* __restrict__ dout,
    __bf16* __restrict__ xn2)
{
  const int row = blockIdx.x;
  const int t = threadIdx.x;
  const size_t base = (size_t)row * D_;
  const size_t st4 = (size_t)NTOK * D_ / 4;
  const size_t i4 = base / 4 + t;
  float4 v = ((const float4*)(x + base))[t];
  const bf16x4 a0 = ((const bf16x4*)opp)[i4];
  const bf16x4 a1 = ((const bf16x4*)opp)[i4 + st4];
  const bf16x4 a2 = ((const bf16x4*)opp)[i4 + 2 * st4];
  const bf16x4 a3 = ((const bf16x4*)opp)[i4 + 3 * st4];
  v.x += (float)a0[0] + (float)a1[0] + (float)a2[0] + (float)a3[0];
  v.y += (float)a0[1] + (float)a1[1] + (float)a2[1] + (float)a3[1];
  v.z += (float)a0[2] + (float)a1[2] + (float)a2[2] + (float)a3[2];
  v.w += (float)a0[3] + (float)a1[3] + (float)a2[3] + (float)a3[3];

  const float4 bb = ((const float4*)b2)[t];
  float4 o4;
  o4.x = v.x + bb.x; o4.y = v.y + bb.y; o4.z = v.z + bb.z; o4.w = v.w + bb.w;
  ((float4*)(dout + base))[t] = o4;

  float s  = v.x + v.y + v.z + v.w;
  float ss = v.x * v.x + v.y * v.y + v.z * v.z + v.w * v.w;
#pragma unroll
  for (int m = 1; m < 64; m <<= 1) {
    s  += __shfl_xor(s, m);
    ss += __shfl_xor(ss, m);
  }
  __shared__ float red[8];
  if ((t & 63) == 0) { red[t >> 6] = s; red[4 + (t >> 6)] = ss; }
  __syncthreads();
  s  = red[0] + red[1] + red[2] + red[3];
  ss = red[4] + red[5] + red[6] + red[7];
  const float mean = s * (1.0f / D_);
  float var = (ss - (float)D_ * mean * mean) * (1.0f / (D_ - 1));
  var = fmaxf(var, 0.0f);
  const float inv = 1.0f / (sqrtf(var) + 1e-6f);
  const float4 al = ((const float4*)alpha)[t];
  const float4 bi = ((const float4*)bias)[t];
  bf16x4 o;
  o.x = (__bf16)(al.x * (v.x - mean) * inv + bi.x);
  o.y = (__bf16)(al.y * (v.y - mean) * inv + bi.y);
  o.z = (__bf16)(al.z * (v.z - mean) * inv + bi.z);
  o.w = (__bf16)(al.w * (v.w - mean) * inv + bi.w);
  ((bf16x4*)(xn2 + base))[t] = o;
}

// ---------------------------------------------------------------------------
// FFN2 reduce: d_out += 4 bf16 partials. Same-thread same-address RMW (safe).
// ---------------------------------------------------------------------------
__global__ __launch_bounds__(256) void ffn2_reduce(
    const __bf16* __restrict__ p0, const __bf16* __restrict__ p1,
    const __bf16* __restrict__ p2, const __bf16* __restrict__ p3,
    float* __restrict__ out)
{
  const int idx4 = blockIdx.x * 256 + threadIdx.x;
  float4 v = ((const float4*)out)[idx4];
  const bf16x4 q0 = ((const bf16x4*)p0)[idx4];
  const bf16x4 q1 = ((const bf16x4*)p1)[idx4];
  const bf16x4 q2 = ((const bf16x4*)p2)[idx4];
  const bf16x4 q3 = ((const bf16x4*)p3)[idx4];
  v.x += (float)q0[0] + (float)q1[0] + (float)q2[0] + (float)q3[0];
  v.y += (float)q0[1] + (float)q1[1] + (float)q2[1] + (float)q3[1];
  v.z += (float)q0[2] + (float)q1[2] + (float)q2[2] + (float)q3[2];
  v.w += (float)q0[3] + (float)q1[3] + (float)q2[3] + (float)q3[3];
  ((float4*)out)[idx4] = v;
}

// ---------------------------------------------------------------------------
// weight f32->bf16 casts (jobs 0-5) + fused LN1 (job 6) in one launch.
// ---------------------------------------------------------------------------
struct CastJobs {
  const float* src[6];
  __bf16* dst[6];
  int n4[6];
};

__global__ __launch_bounds__(256) void cast_ln_kernel(
    CastJobs cj, const float* __restrict__ x, const float* __restrict__ alpha,
    const float* __restrict__ bias, __bf16* __restrict__ xn1)
{
  const int j = blockIdx.y;
  if (j < 6) {
    const int i = blockIdx.x * 256 + threadIdx.x;
    if (i < cj.n4[j]) {
      float4 v = ((const float4*)cj.src[j])[i];
      bf16x4 o;
      o.x = (__bf16)v.x; o.y = (__bf16)v.y; o.z = (__bf16)v.z; o.w = (__bf16)v.w;
      ((bf16x4*)cj.dst[j])[i] = o;
    }
    return;
  }
  const int row = blockIdx.x;
  const int t = threadIdx.x;
  const float4 v = ((const float4*)(x + (size_t)row * D_))[t];
  float s  = v.x + v.y + v.z + v.w;
  float ss = v.x * v.x + v.y * v.y + v.z * v.z + v.w * v.w;
#pragma unroll
  for (int m = 1; m < 64; m <<= 1) {
    s  += __shfl_xor(s, m);
    ss += __shfl_xor(ss, m);
  }
  __shared__ float red[8];
  if ((t & 63) == 0) { red[t >> 6] = s; red[4 + (t >> 6)] = ss; }
  __syncthreads();
  s  = red[0] + red[1] + red[2] + red[3];
  ss = red[4] + red[5] + red[6] + red[7];
  const float mean = s * (1.0f / D_);
  float var = (ss - (float)D_ * mean * mean) * (1.0f / (D_ - 1));
  var = fmaxf(var, 0.0f);
  const float inv = 1.0f / (sqrtf(var) + 1e-6f);
  const float4 al = ((const float4*)alpha)[t];
  const float4 bi = ((const float4*)bias)[t];
  bf16x4 o;
  o.x = (__bf16)(al.x * (v.x - mean) * inv + bi.x);
  o.y = (__bf16)(al.y * (v.y - mean) * inv + bi.y);
  o.z = (__bf16)(al.z * (v.z - mean) * inv + bi.z);
  o.w = (__bf16)(al.w * (v.w - mean) * inv + bi.w);
  ((bf16x4*)(xn1 + (size_t)row * D_))[t] = o;
}

// ---------------------------------------------------------------------------
// flash attention, BQ=128. R4: P stays IN REGISTERS (T12): swapped QK^T makes
// lane&15 = q-col; the sacc->PV-A-frag lane permutation is exactly
// permlane32_swap (i-selection lands on lane bit5) then permlane16_swap
// (g-selection on bit4): H0 = P(i=2s+b5, g=2*b4) = frag e0-3, H1 = g=2*b4+1
// = e4-7. Removes 8 ds_write + 4 ds_read + the write->read chain per iter,
// kills the Ps stride-72 bank conflicts, frees 18KB LDS (Q gets a dedicated
// buffer; no overlay hazard). sacc zero-init removed via MFMA-with-z4-C.
// K/V dbuf + single barrier per iter (R2); lsum via P@ones MFMA (R3).
// ---------------------------------------------------------------------------
__global__ __launch_bounds__(256) void attn_kernel(
    const __bf16* __restrict__ qg, const __bf16* __restrict__ kg,
    const __bf16* __restrict__ vtg, const int* __restrict__ mask,
    __bf16* __restrict__ av)
{
  __shared__ __align__(16) __bf16 Ks[2][4096];   // 16 KB
  __shared__ __align__(16) __bf16 Vt[2][4096];   // 16 KB
  __shared__ __align__(16) __bf16 Qs[8192];      // 16 KB
  __shared__ int Dd[32];                         // per-kv-chunk dirty flags

  const int t = threadIdx.x, lane = t & 63, wv = t >> 6;
  const int l15 = lane & 15, q4 = lane >> 4;
  const bool hi16 = (lane & 16) != 0, hi32 = (lane & 32) != 0;
  const int bh = blockIdx.x;
  const int b = bh >> 4, h = bh & (H_ - 1);
  const int q0 = blockIdx.y * 128;

  const int srow = lane & 7, sc8 = lane >> 3;
  const __bf16* qg0 = qg + (size_t)(b * S_ + q0 + 32 * wv + srow) * D_ + h * DK_ + sc8 * 8;
  __bf16* lQ = Qs + wv * 2048;
#pragma unroll
  for (int p = 0; p < 4; ++p)
    ld16(qg0 + (size_t)(8 * p) * D_, lQ + 512 * p);

  const __bf16* kg0 = kg + (size_t)(b * S_ + 16 * wv + srow) * D_ + h * DK_ + sc8 * 8;
  const __bf16* vt0 = vtg + (size_t)(bh * DK_ + 16 * wv + srow) * S_ + sc8 * 8;

  if (t < 32) Dd[t] = 0;

  // stage kv-tile 0 into buf 0
  ld16(kg0,                  Ks[0] + wv * 1024);
  ld16(kg0 + (size_t)8 * D_, Ks[0] + wv * 1024 + 512);
  ld16(vt0,                  Vt[0] + wv * 1024);
  ld16(vt0 + (size_t)8 * S_, Vt[0] + wv * 1024 + 512);

  __syncthreads();   // Dd init visible; drains Q/KV0 staging

  // one-time mask scan: thread t covers kv = 8t..8t+8 (chunk t>>3)
  {
    const int4* m4 = (const int4*)(mask + (size_t)b * S_) + t * 2;
    const int4 a = m4[0], c = m4[1];
    const bool anyz = (a.x == 0) | (a.y == 0) | (a.z == 0) | (a.w == 0) |
                      (c.x == 0) | (c.y == 0) | (c.z == 0) | (c.w == 0);
    if (anyz) Dd[t >> 3] = 1;
  }
  __syncthreads();
  const bool blockDirty = (__ballot(Dd[lane & 31] != 0) != 0ull);

  const int fb = ((l15 >> 3) << 9) + (q4 << 6) + ((l15 & 7) << 3);
  const int mrow = b * S_;

  // Q B-frags (Qs is never rewritten -> no hazard)
  bf16x8 bq[2][2];
#pragma unroll
  for (int j = 0; j < 2; ++j)
#pragma unroll
    for (int s = 0; s < 2; ++s)
      bq[j][s] = *(const bf16x8*)(lQ + j * 1024 + s * 256 + fb);

  bf16x8 bones;
#pragma unroll
  for (int e = 0; e < 8; ++e) bones[e] = (__bf16)1.0f;
  const f32x4 z4 = {0.f, 0.f, 0.f, 0.f};

  f32x4 lacc[2];
  f32x4 oacc[2][4];
#pragma unroll
  for (int m = 0; m < 2; ++m) {
    lacc[m] = z4;
#pragma unroll
    for (int jd = 0; jd < 4; ++jd) oacc[m][jd] = z4;
  }

  for (int kv0 = 0; kv0 < S_; kv0 += 64) {
    const int buf = (kv0 >> 6) & 1;
    if (kv0 + 64 < S_) {   // prefetch next kv-tile into buf^1
      const size_t nk = (size_t)(kv0 + 64);
      ld16(kg0 + nk * D_,              Ks[buf ^ 1] + wv * 1024);
      ld16(kg0 + (nk + 8) * D_,        Ks[buf ^ 1] + wv * 1024 + 512);
      ld16(vt0 + nk,                   Vt[buf ^ 1] + wv * 1024);
      ld16(vt0 + (size_t)8 * S_ + nk,  Vt[buf ^ 1] + wv * 1024 + 512);
    }

    // S^T = K Q^T : rows kv (4 i-tiles), cols q (wave's 2 j-slices of 16)
    f32x4 sacc[4][2];
    __builtin_amdgcn_s_setprio(1);
#pragma unroll
    for (int i = 0; i < 4; ++i) {
      const bf16x8 ak0 = *(const bf16x8*)(Ks[buf] + i * 1024 + fb);
      const bf16x8 ak1 = *(const bf16x8*)(Ks[buf] + i * 1024 + fb + 256);
      sacc[i][0] = __builtin_amdgcn_mfma_f32_16x16x32_bf16(ak0, bq[0][0], z4, 0, 0, 0);
      sacc[i][1] = __builtin_amdgcn_mfma_f32_16x16x32_bf16(ak0, bq[1][0], z4, 0, 0, 0);
      sacc[i][0] = __builtin_amdgcn_mfma_f32_16x16x32_bf16(ak1, bq[0][1], sacc[i][0], 0, 0, 0);
      sacc[i][1] = __builtin_amdgcn_mfma_f32_16x16x32_bf16(ak1, bq[1][1], sacc[i][1], 0, 0, 0);
    }
    __builtin_amdgcn_s_setprio(0);

    if (blockDirty && Dd[kv0 >> 6]) {   // cold path (all-ones mask: never)
#pragma unroll
      for (int i = 0; i < 4; ++i)
#pragma unroll
        for (int r = 0; r < 4; ++r)
          if (mask[mrow + kv0 + 16 * i + 4 * q4 + r] == 0) {
            sacc[i][0][r] = -1e30f;
            sacc[i][1][r] = -1e30f;
          }
    }

    // fixed-max softmax in place
#pragma unroll
    for (int i = 0; i < 4; ++i)
#pragma unroll
      for (int j = 0; j < 2; ++j)
#pragma unroll
        for (int r = 0; r < 4; ++r)
          sacc[i][j][r] = EXP2(sacc[i][j][r]);

    // P -> PV A-frags fully in registers (cvt_pk + permlane32/16 swaps)
    bf16x8 ap[2][2];
#pragma unroll
    for (int j = 0; j < 2; ++j)
#pragma unroll
      for (int s = 0; s < 2; ++s) {
        const int pa0 = packbf(sacc[2 * s][j][0],     sacc[2 * s][j][1]);
        const int pa1 = packbf(sacc[2 * s][j][2],     sacc[2 * s][j][3]);
        const int pb0 = packbf(sacc[2 * s + 1][j][0], sacc[2 * s + 1][j][1]);
        const int pb1 = packbf(sacc[2 * s + 1][j][2], sacc[2 * s + 1][j][3]);
        int g0, g1, g2, g3, h0, h1, h2, h3;
        swap32(pa0, pb0, g0, g1, hi32);   // w=0: (G0,G1)
        swap32(pa1, pb1, g2, g3, hi32);   // w=1
        swap16(g0, g1, h0, h1, hi16);     // (H0w0, H1w0)
        swap16(g2, g3, h2, h3, hi16);     // (H0w1, H1w1)
        i32x4 fw; fw[0] = h0; fw[1] = h2; fw[2] = h1; fw[3] = h3;
        ap[j][s] = __builtin_bit_cast(bf16x8, fw);
      }

    // O += P V ; l += P @ ones (MFMA-pipe row-sum)
    __builtin_amdgcn_s_setprio(1);
#pragma unroll
    for (int jd = 0; jd < 4; ++jd)
#pragma unroll
      for (int s = 0; s < 2; ++s) {
        bf16x8 bv = *(const bf16x8*)(Vt[buf] + jd * 1024 + fb + s * 256);
#pragma unroll
        for (int m = 0; m < 2; ++m)
          oacc[m][jd] = __builtin_amdgcn_mfma_f32_16x16x32_bf16(ap[m][s], bv, oacc[m][jd], 0, 0, 0);
      }
#pragma unroll
    for (int m = 0; m < 2; ++m)
#pragma unroll
      for (int s = 0; s < 2; ++s)
        lacc[m] = __builtin_amdgcn_mfma_f32_16x16x32_bf16(ap[m][s], bones, lacc[m], 0, 0, 0);
    __builtin_amdgcn_s_setprio(0);

    __syncthreads();   // drains prefetch (RAW) + proves buf read done (WAR)
  }

  // lacc[m][r] = l for q-row (wv*32 + 16m + q4*4 + r) — already O-row-owned.
#pragma unroll
  for (int m = 0; m < 2; ++m) {
    f32x4 lt;
#pragma unroll
    for (int r = 0; r < 4; ++r) lt[r] = 1.0f / lacc[m][r];
#pragma unroll
    for (int jd = 0; jd < 4; ++jd)
#pragma unroll
      for (int r = 0; r < 4; ++r) {
        int tok = b * S_ + q0 + wv * 32 + 16 * m + q4 * 4 + r;
        int c   = h * DK_ + jd * 16 + l15;
        av[(size_t)tok * D_ + c] = (__bf16)(oacc[m][jd][r] * lt[r]);
      }
  }
}

// ---------------------------------------------------------------------------
// Workspace map (80MB, stream-order verified):
//  0-2 wqb | 2-4 wkb | 4-6 wvb | 6-8 wob | 8-16 w1b | 16-24 w2b | 24-32 xn1
//  32-40 qb | 40-48 kb | 48-56 vtb | 56-64 avb
//  opp (oproj bf16 partials 4x8MB) = 24-56  (xn1/qb/kb/vtb dead)
//  xn2 = 56-64 (over avb, dead after oproj GEMM)
//  hb (ffn1 out, 32MB) = 24-56 (opp dead after oproj_ln)
//  ffn2 partials fp0..3 = {0-8, 8-16, 56-64, 64-72} (all dead at ffn2 time)
// ---------------------------------------------------------------------------
extern "C" void kernel_launch(void* const* d_in, const int* in_sizes, int n_in,
                              void* d_out, int out_size, void* d_ws, size_t ws_size,
                              hipStream_t stream) {
  const float* x      = (const float*)d_in[0];
  const int*   mask   = (const int*)d_in[1];
  const float* wq     = (const float*)d_in[2];
  const float* wk     = (const float*)d_in[3];
  const float* wv     = (const float*)d_in[4];
  const float* wo     = (const float*)d_in[5];
  const float* w1     = (const float*)d_in[6];
  const float* b1     = (const float*)d_in[7];
  const float* w2     = (const float*)d_in[8];
  const float* b2     = (const float*)d_in[9];
  const float* alpha1 = (const float*)d_in[10];
  const float* bias1  = (const float*)d_in[11];
  const float* alpha2 = (const float*)d_in[12];
  const float* bias2  = (const float*)d_in[13];

  char* ws = (char*)d_ws;
  __bf16* wqb = (__bf16*)(ws + ((size_t)0 << 20));
  __bf16* wkb = (__bf16*)(ws + ((size_t)2 << 20));
  __bf16* wvb = (__bf16*)(ws + ((size_t)4 << 20));
  __bf16* wob = (__bf16*)(ws + ((size_t)6 << 20));
  __bf16* w1b = (__bf16*)(ws + ((size_t)8 << 20));
  __bf16* w2b = (__bf16*)(ws + ((size_t)16 << 20));
  __bf16* xn1 = (__bf16*)(ws + ((size_t)24 << 20));
  __bf16* qb  = (__bf16*)(ws + ((size_t)32 << 20));
  __bf16* kb  = (__bf16*)(ws + ((size_t)40 << 20));
  __bf16* vtb = (__bf16*)(ws + ((size_t)48 << 20));
  __bf16* avb = (__bf16*)(ws + ((size_t)56 << 20));
  __bf16* opp = (__bf16*)(ws + ((size_t)24 << 20));   // oproj partials 4x8MB
  __bf16* xn2 = (__bf16*)(ws + ((size_t)56 << 20));   // over avb
  __bf16* hb  = (__bf16*)(ws + ((size_t)24 << 20));   // over opp (dead)
  __bf16* fp0 = (__bf16*)(ws + ((size_t)0 << 20));
  __bf16* fp1 = (__bf16*)(ws + ((size_t)8 << 20));
  __bf16* fp2 = (__bf16*)(ws + ((size_t)56 << 20));   // over xn2 (dead)
  __bf16* fp3 = (__bf16*)(ws + ((size_t)64 << 20));

  CastJobs cj;
  cj.src[0] = wq; cj.dst[0] = wqb; cj.n4[0] = D_ * D_ / 4;
  cj.src[1] = wk; cj.dst[1] = wkb; cj.n4[1] = D_ * D_ / 4;
  cj.src[2] = wv; cj.dst[2] = wvb; cj.n4[2] = D_ * D_ / 4;
  cj.src[3] = wo; cj.dst[3] = wob; cj.n4[3] = D_ * D_ / 4;
  cj.src[4] = w1; cj.dst[4] = w1b; cj.n4[4] = DFF_ * D_ / 4;
  cj.src[5] = w2; cj.dst[5] = w2b; cj.n4[5] = DFF_ * D_ / 4;

  cast_ln_kernel<<<dim3(DFF_ * D_ / 4 / 256, 7), 256, 0, stream>>>(
      cj, x, alpha1, bias1, xn1);

  gemm_qkv_256<<<dim3(D_ / 256, NTOK / 256, 3), 512, 0, stream>>>(
      xn1, wqb, wkb, wvb, qb, kb, vtb);

  attn_kernel<<<dim3(B_ * H_, S_ / 128), 256, 0, stream>>>(qb, kb, vtb, mask, avb);

  gemm_oproj_sk4<<<dim3(D_ / 256, NTOK / 256, 4), 512, 0, stream>>>(
      avb, wob, opp);

  oproj_ln_reduce<<<dim3(NTOK), 256, 0, stream>>>(
      x, opp, alpha2, bias2, b2, (float*)d_out, xn2);

  gemm_ffn1_256<<<dim3(DFF_ / 256, NTOK / 256), 512, 0, stream>>>(
      xn2, w1b, hb, b1);

  gemm_ffn2_sk4<<<dim3(D_ / 256, NTOK / 256, 4), 512, 0, stream>>>(
      hb, w2b, fp0, fp1, fp2, fp3);

  ffn2_reduce<<<dim3(NTOK * D_ / 4 / 256), 256, 0, stream>>>(
      fp0, fp1, fp2, fp3, (float*)d_out);
}